// Round 2
// baseline (80.407 us; speedup 1.0000x reference)
//
#include <hip/hip_runtime.h>

#define V 96
#define VV (V * V)
#define B_ 4
#define N_ 32
#define P_ 32
#define G_ 4               // polygon groups per batch (atomic-free partial max)
#define NPG (N_ / G_)      // 8 polygons per group
#define TILES (VV / 256)   // 36 pixel tiles per (b,g)

// One block = (b, group, 256-pixel tile). Loops the group's 8 polygons,
// keeps a running max mask, stores directly (no init / atomics needed).
__global__ __launch_bounds__(256) void mask_kernel(
    const float* __restrict__ poly,       // (B,N,P,2)
    const float* __restrict__ validity,   // (B,N)
    float* __restrict__ combined4)        // (B,G,VV) partial maxima
{
    const int bg  = blockIdx.x / TILES;                  // b*G_ + g
    const int pix = (blockIdx.x % TILES) * 256 + threadIdx.x;
    const int b   = bg >> 2;
    const int g   = bg & (G_ - 1);

    __shared__ float sx0[NPG][P_], sy0[NPG][P_], sex[NPG][P_], sey[NPG][P_],
                     srq[NPG][P_], sry[NPG][P_];
    {
        // 256 threads <-> 8 polys x 32 edges: each preps one edge
        const int t  = threadIdx.x;
        const int nl = t >> 5, p = t & 31, pn = (p + 1) & 31;
        const float* base = poly + (size_t)(b * N_ + g * NPG + nl) * (P_ * 2);
        float x0 = base[p * 2],  y0 = base[p * 2 + 1];
        float x1 = base[pn * 2], y1 = base[pn * 2 + 1];
        float ex = x1 - x0, ey = y1 - y0;
        sx0[nl][p] = x0; sy0[nl][p] = y0; sex[nl][p] = ex; sey[nl][p] = ey;
        srq[nl][p] = __builtin_amdgcn_rcpf(ex * ex + ey * ey + 1e-8f);
        sry[nl][p] = __builtin_amdgcn_rcpf(ey + 1e-8f);
    }
    __syncthreads();

    // exact fp32 division to match numpy's grid (borderline y-comparisons)
    const int py_i = pix / V, px_i = pix - py_i * V;
    const float px = (float)px_i / 95.0f;
    const float py = (float)py_i / 95.0f;

    float best = 0.0f;
    for (int nl = 0; nl < NPG; ++nl) {
        // validity is identical across the block -> wave-uniform skip
        if (validity[b * N_ + g * NPG + nl] < 0.5f) continue;

        float mind2 = 1e30f;
        int   par   = 0;
        #pragma unroll
        for (int p = 0; p < P_; ++p) {
            const int pn = (p + 1) & (P_ - 1);
            float x0 = sx0[nl][p], y0 = sy0[nl][p];
            float y1 = sy0[nl][pn];          // exact vertex value for compare
            float ex = sex[nl][p], ey = sey[nl][p];

            float vx = px - x0, vy = py - y0;
            float t  = (vx * ex + vy * ey) * srq[nl][p];
            t = fminf(fmaxf(t, 0.0f), 1.0f);
            float dx = vx - t * ex, dy = vy - t * ey;
            float d2 = dx * dx + dy * dy;
            mind2 = fminf(mind2, d2);

            bool c0 = (y0 <= py);
            bool c1 = (y1 <= py);
            float inter_x = x0 + ex * (vy * sry[nl][p]);  // vy == py - y0
            par ^= (int)((c0 != c1) & (inter_x > px));
        }
        float mind = sqrtf(mind2);
        float sdf  = par ? -mind : mind;
        // sigmoid(-100*sdf); rcp approx (~1ulp) irrelevant vs 2e-2 threshold
        float m = __builtin_amdgcn_rcpf(1.0f + __expf(sdf * 100.0f));
        best = fmaxf(best, m);
    }
    combined4[(size_t)bg * VV + pix] = best;
}

__global__ __launch_bounds__(256) void expand_kernel(
    const float* __restrict__ combined4,  // (B,G,VV)
    const float* __restrict__ attr,       // (B,8)
    float4* __restrict__ out)             // (B,V,V,V)
{
    const int gid = blockIdx.x * 256 + threadIdx.x;   // B*V*V*(V/4) elems
    const int row = gid / (V / 4);
    const int x4  = gid - row * (V / 4);
    const int y   = row % V;
    const int t_  = row / V;
    const int d   = t_ % V;
    const int b   = t_ / V;

    float a  = attr[b * 8];
    float nh = fminf(fmaxf(a, 0.0f), 1.0f);
    float hv = fminf(fmaxf(rintf(nh * (float)V), 1.0f), (float)V);  // half-even like numpy
    float keep = ((float)d < hv) ? 1.0f : 0.0f;

    const float4* c4 = (const float4*)combined4;
    const int pixoff = y * (V / 4) + x4;
    float4 c0 = c4[(size_t)(b * G_ + 0) * (VV / 4) + pixoff];
    float4 c1 = c4[(size_t)(b * G_ + 1) * (VV / 4) + pixoff];
    float4 c2 = c4[(size_t)(b * G_ + 2) * (VV / 4) + pixoff];
    float4 c3 = c4[(size_t)(b * G_ + 3) * (VV / 4) + pixoff];
    float4 r;
    r.x = fmaxf(fmaxf(c0.x, c1.x), fmaxf(c2.x, c3.x)) * keep;
    r.y = fmaxf(fmaxf(c0.y, c1.y), fmaxf(c2.y, c3.y)) * keep;
    r.z = fmaxf(fmaxf(c0.z, c1.z), fmaxf(c2.z, c3.z)) * keep;
    r.w = fmaxf(fmaxf(c0.w, c1.w), fmaxf(c2.w, c3.w)) * keep;
    out[gid] = r;
}

extern "C" void kernel_launch(void* const* d_in, const int* in_sizes, int n_in,
                              void* d_out, int out_size, void* d_ws, size_t ws_size,
                              hipStream_t stream) {
    const float* polygons = (const float*)d_in[0];   // (4,32,32,2)
    const float* attrs    = (const float*)d_in[1];   // (4,8)
    const float* validity = (const float*)d_in[2];   // (4,32)
    float* out       = (float*)d_out;                // (4,96,96,96)
    float* combined4 = (float*)d_ws;                 // (4,4,9216) floats, written before read

    mask_kernel<<<B_ * G_ * TILES, 256, 0, stream>>>(polygons, validity, combined4);
    expand_kernel<<<(B_ * V * V * (V / 4)) / 256, 256, 0, stream>>>(combined4, attrs, (float4*)out);
}

// Round 3
// 78.018 us; speedup vs baseline: 1.0306x; 1.0306x over previous
//
#include <hip/hip_runtime.h>

#define V 96
#define VV (V * V)
#define B_ 4
#define N_ 32
#define P_ 32
#define TILES (VV / 256)   // 36 pixel tiles per (b,n)

// One block = (b, n, 256-pixel tile). Computes one polygon's soft mask for
// 256 pixels and stores it to ws slot (b*N+n, pix). Invalid polygon -> no
// store (expand never reads those slots). No atomics, no init required.
__global__ __launch_bounds__(256) void mask_kernel(
    const float* __restrict__ poly,       // (B,N,P,2)
    const float* __restrict__ validity,   // (B,N)
    float* __restrict__ partial)          // (B*N, VV) per-polygon masks
{
    const int bn  = blockIdx.x / TILES;                  // b*N + n, block-uniform
    const int pix = (blockIdx.x % TILES) * 256 + threadIdx.x;

    if (validity[bn] < 0.5f) return;                     // block-uniform skip

    __shared__ float sx0[P_], sy0[P_], sex[P_], sey[P_], srq[P_], sry[P_];
    if (threadIdx.x < P_) {
        const int p  = threadIdx.x;
        const int pn = (p + 1) & (P_ - 1);
        const float* base = poly + (size_t)bn * (P_ * 2);
        float x0 = base[p * 2],  y0 = base[p * 2 + 1];
        float x1 = base[pn * 2], y1 = base[pn * 2 + 1];
        float ex = x1 - x0, ey = y1 - y0;
        sx0[p] = x0; sy0[p] = y0; sex[p] = ex; sey[p] = ey;
        srq[p] = __builtin_amdgcn_rcpf(ex * ex + ey * ey + 1e-8f);
        sry[p] = __builtin_amdgcn_rcpf(ey + 1e-8f);
    }
    __syncthreads();

    // exact fp32 division to match numpy's grid (borderline y-comparisons)
    const int py_i = pix / V, px_i = pix - py_i * V;
    const float px = (float)px_i / 95.0f;
    const float py = (float)py_i / 95.0f;

    float mind2 = 1e30f;
    int   par   = 0;
    #pragma unroll
    for (int p = 0; p < P_; ++p) {
        const int pn = (p + 1) & (P_ - 1);
        float x0 = sx0[p], y0 = sy0[p];
        float y1 = sy0[pn];                 // exact vertex value for compare
        float ex = sex[p], ey = sey[p];

        float vx = px - x0, vy = py - y0;
        float t  = (vx * ex + vy * ey) * srq[p];
        t = fminf(fmaxf(t, 0.0f), 1.0f);
        float dx = vx - t * ex, dy = vy - t * ey;
        float d2 = dx * dx + dy * dy;
        mind2 = fminf(mind2, d2);

        bool c0 = (y0 <= py);
        bool c1 = (y1 <= py);
        float inter_x = x0 + ex * (vy * sry[p]);   // vy == py - y0
        par ^= (int)((c0 != c1) & (inter_x > px));
    }
    float mind = sqrtf(mind2);
    float sdf  = par ? -mind : mind;
    float m = __builtin_amdgcn_rcpf(1.0f + __expf(sdf * 100.0f));

    partial[(size_t)bn * VV + pix] = m;
}

// One block = (b, y, d-quarter). Phase 1: threads<96 reduce max over valid n
// for one (b,y) pixel row (96 x values) into LDS. Phase 2: 192 threads write
// 24 d-slices x 96 x (as float4) with the depth mask applied.
__global__ __launch_bounds__(192) void expand_kernel(
    const float* __restrict__ partial,    // (B*N, VV)
    const float* __restrict__ validity,   // (B,N)
    const float* __restrict__ attr,       // (B,8)
    float4* __restrict__ out)             // (B,V,V,V)
{
    const int bid = blockIdx.x;           // B * V * 4 = 1536
    const int b   = bid / (V * 4);
    const int rem = bid - b * (V * 4);
    const int y   = rem >> 2;
    const int q   = rem & 3;
    const int t   = threadIdx.x;

    __shared__ float red[V];              // reduced row, 96 floats

    if (t < V) {
        const int x = t;
        float m = 0.0f;
        #pragma unroll
        for (int n = 0; n < N_; ++n) {
            if (validity[b * N_ + n] >= 0.5f) {   // uniform scalar branch
                m = fmaxf(m, partial[(size_t)(b * N_ + n) * VV + y * V + x]);
            }
        }
        red[x] = m;
    }
    __syncthreads();

    float a  = attr[b * 8];
    float nh = fminf(fmaxf(a, 0.0f), 1.0f);
    float hv = fminf(fmaxf(rintf(nh * (float)V), 1.0f), (float)V);  // half-even like numpy

    const float4* red4 = (const float4*)red;
    #pragma unroll
    for (int it = 0; it < 3; ++it) {
        const int idx = it * 192 + t;     // 0..575 = 24 d x 24 x4
        const int dl  = idx / 24;
        const int x4  = idx - dl * 24;
        const int d   = q * 24 + dl;
        const float keep = ((float)d < hv) ? 1.0f : 0.0f;
        float4 c = red4[x4];
        out[((size_t)(b * V + d) * V + y) * (V / 4) + x4] =
            make_float4(c.x * keep, c.y * keep, c.z * keep, c.w * keep);
    }
}

extern "C" void kernel_launch(void* const* d_in, const int* in_sizes, int n_in,
                              void* d_out, int out_size, void* d_ws, size_t ws_size,
                              hipStream_t stream) {
    const float* polygons = (const float*)d_in[0];   // (4,32,32,2)
    const float* attrs    = (const float*)d_in[1];   // (4,8)
    const float* validity = (const float*)d_in[2];   // (4,32)
    float* out     = (float*)d_out;                  // (4,96,96,96)
    float* partial = (float*)d_ws;                   // (128, 9216) floats

    mask_kernel<<<B_ * N_ * TILES, 256, 0, stream>>>(polygons, validity, partial);
    expand_kernel<<<B_ * V * 4, 192, 0, stream>>>(partial, validity, attrs, (float4*)out);
}